// Round 11
// baseline (262.035 us; speedup 1.0000x reference)
//
#include <hip/hip_runtime.h>
#include <hip/hip_bf16.h>
#include <math.h>

#define B 32
#define P 100
#define N 1000
#define D 128

constexpr float SQRT_D_INV = 1.0f / 11.313708498984761f;
constexpr float CLIPV = 10.0f;

typedef unsigned short ushortx;

__device__ __forceinline__ void fma4(float4& a, float s, const float4& b) {
    a.x = fmaf(s, b.x, a.x);
    a.y = fmaf(s, b.y, a.y);
    a.z = fmaf(s, b.z, a.z);
    a.w = fmaf(s, b.w, a.w);
}

// bf16 pack (RNE) / unpack (shift) — manual, no API surprises.
__device__ __forceinline__ ushortx f2bf(float f) {
    unsigned u = __float_as_uint(f);
    unsigned lsb = (u >> 16) & 1u;
    return (ushortx)((u + 0x7FFFu + lsb) >> 16);
}
__device__ __forceinline__ float bf2f(ushortx s) {
    return __uint_as_float(((unsigned)s) << 16);
}

// ---------------------------------------------------------------------------
// K0: prep = weight transposes (blocks 0..127) + nodes transpose (rest).
// ---------------------------------------------------------------------------
#define TT 64
__global__ __launch_bounds__(256) void prep_kernel(
        const float* __restrict__ nodes,
        const float* __restrict__ Wk,  const float* __restrict__ Wv,
        const float* __restrict__ Wqf, const float* __restrict__ Wql,
        float* __restrict__ wkT,  float* __restrict__ wvT,
        float* __restrict__ wqfT, float* __restrict__ wqlT,
        float* __restrict__ nodesT) {
    const int t = threadIdx.x;
    if (blockIdx.x < D) {
        const int e = blockIdx.x;
        const int d = t & 127;
        if ((t >> 7) == 0) {
            wkT[e * D + d] = Wk[d * D + e];
            wvT[e * D + d] = Wv[d * D + e];
        } else {
            wqfT[e * D + d] = Wqf[d * D + e];
            wqlT[e * D + d] = Wql[d * D + e];
        }
        return;
    }
    __shared__ float sh[TT][D + 1];
    const int blk = blockIdx.x - D;
    const int ntiles = (N + TT - 1) / TT;   // 16
    const int b  = blk / ntiles;
    const int n0 = (blk % ntiles) * TT;
    const int rows = min(TT, N - n0);

    const float4* src = (const float4*)(nodes + ((long)b * N + n0) * D);
    for (int i = t; i < rows * (D / 4); i += 256) {
        int r = i >> 5, c = i & 31;
        float4 v = src[(long)r * (D / 4) + c];
        sh[r][c * 4 + 0] = v.x; sh[r][c * 4 + 1] = v.y;
        sh[r][c * 4 + 2] = v.z; sh[r][c * 4 + 3] = v.w;
    }
    __syncthreads();

    const int nl = t & 63;
    const int eg = t >> 6;
    if (nl < rows) {
        #pragma unroll
        for (int k = 0; k < 32; ++k) {
            int e = eg * 32 + k;
            nodesT[((long)b * D + e) * N + n0 + nl] = sh[nl][e];
        }
    }
}

// ---------------------------------------------------------------------------
// K1: ek = exp(nodes @ WkT), ekv = ek * (nodes @ WvT) — stored as bf16.
// ---------------------------------------------------------------------------
#define R1 32
__global__ __launch_bounds__(256) void kv_kernel(
        const float* __restrict__ nodes,
        const float* __restrict__ wkT,
        const float* __restrict__ wvT,
        ushortx* __restrict__ ekh,
        ushortx* __restrict__ evh) {
    __shared__ float sh[R1][D];
    const int t = threadIdx.x;
    const int dq = t & 31;
    const int rl = t >> 5;
    const long row0 = (long)blockIdx.x * R1;

    const float4* src = (const float4*)(nodes + row0 * D);
    float4* dst = (float4*)(&sh[0][0]);
    #pragma unroll
    for (int i = 0; i < (R1 * D / 4) / 256; ++i)
        dst[t + i * 256] = src[t + i * 256];
    __syncthreads();

    float4 ka[4], va[4];
    #pragma unroll
    for (int rr = 0; rr < 4; ++rr) {
        ka[rr] = make_float4(0.f, 0.f, 0.f, 0.f);
        va[rr] = make_float4(0.f, 0.f, 0.f, 0.f);
    }

    const float* wkp = wkT + dq * 4;
    const float* wvp = wvT + dq * 4;

    float4 cwk[4], cwv[4];
    #pragma unroll
    for (int ee = 0; ee < 4; ++ee) {
        cwk[ee] = *(const float4*)(wkp + ee * D);
        cwv[ee] = *(const float4*)(wvp + ee * D);
    }

    for (int e0 = 0; e0 < D; e0 += 4) {
        float4 nwk[4], nwv[4];
        if (e0 + 4 < D) {
            #pragma unroll
            for (int ee = 0; ee < 4; ++ee) {
                nwk[ee] = *(const float4*)(wkp + (e0 + 4 + ee) * D);
                nwv[ee] = *(const float4*)(wvp + (e0 + 4 + ee) * D);
            }
        }
        #pragma unroll
        for (int rr = 0; rr < 4; ++rr) {
            float4 s4 = *(const float4*)(&sh[rl * 4 + rr][e0]);
            fma4(ka[rr], s4.x, cwk[0]); fma4(ka[rr], s4.y, cwk[1]);
            fma4(ka[rr], s4.z, cwk[2]); fma4(ka[rr], s4.w, cwk[3]);
            fma4(va[rr], s4.x, cwv[0]); fma4(va[rr], s4.y, cwv[1]);
            fma4(va[rr], s4.z, cwv[2]); fma4(va[rr], s4.w, cwv[3]);
        }
        #pragma unroll
        for (int ee = 0; ee < 4; ++ee) { cwk[ee] = nwk[ee]; cwv[ee] = nwv[ee]; }
    }

    #pragma unroll
    for (int rr = 0; rr < 4; ++rr) {
        long row = row0 + rl * 4 + rr;
        float ex = __expf(ka[rr].x), ey = __expf(ka[rr].y);
        float ez = __expf(ka[rr].z), ew = __expf(ka[rr].w);
        ushort4 eb4, ev4;
        eb4.x = f2bf(ex); eb4.y = f2bf(ey); eb4.z = f2bf(ez); eb4.w = f2bf(ew);
        ev4.x = f2bf(ex * va[rr].x); ev4.y = f2bf(ey * va[rr].y);
        ev4.z = f2bf(ez * va[rr].z); ev4.w = f2bf(ew * va[rr].w);
        *(ushort4*)(ekh + row * D + dq * 4) = eb4;
        *(ushort4*)(evh + row * D + dq * 4) = ev4;
    }
}

// ---------------------------------------------------------------------------
// K2: qsig = sigmoid(q1 @ Wqf^T + qlast @ Wql^T)  (R8-proven)
// ---------------------------------------------------------------------------
#define R2 16
__global__ __launch_bounds__(256) void q_kernel(
        const float* __restrict__ q1,
        const float* __restrict__ qlast,
        const float* __restrict__ wqfT,
        const float* __restrict__ wqlT,
        float* __restrict__ qsig) {
    __shared__ float sh1[R2][D];
    __shared__ float sh2[R2][D];
    const int t = threadIdx.x;
    const int dq = t & 31;
    const int rl = t >> 5;
    const long row0 = (long)blockIdx.x * R2;

    const float4* s1 = (const float4*)(q1 + row0 * D);
    const float4* s2 = (const float4*)(qlast + row0 * D);
    float4* d1 = (float4*)(&sh1[0][0]);
    float4* d2 = (float4*)(&sh2[0][0]);
    #pragma unroll
    for (int i = 0; i < (R2 * D / 4) / 256; ++i) {
        d1[t + i * 256] = s1[t + i * 256];
        d2[t + i * 256] = s2[t + i * 256];
    }
    __syncthreads();

    float4 acc[2];
    acc[0] = make_float4(0.f, 0.f, 0.f, 0.f);
    acc[1] = make_float4(0.f, 0.f, 0.f, 0.f);

    const float* wfp = wqfT + dq * 4;
    const float* wlp = wqlT + dq * 4;

    float4 cwf[4], cwl[4];
    #pragma unroll
    for (int ee = 0; ee < 4; ++ee) {
        cwf[ee] = *(const float4*)(wfp + ee * D);
        cwl[ee] = *(const float4*)(wlp + ee * D);
    }

    for (int e0 = 0; e0 < D; e0 += 4) {
        float4 nwf[4], nwl[4];
        if (e0 + 4 < D) {
            #pragma unroll
            for (int ee = 0; ee < 4; ++ee) {
                nwf[ee] = *(const float4*)(wfp + (e0 + 4 + ee) * D);
                nwl[ee] = *(const float4*)(wlp + (e0 + 4 + ee) * D);
            }
        }
        #pragma unroll
        for (int rr = 0; rr < 2; ++rr) {
            float4 a4 = *(const float4*)(&sh1[rl * 2 + rr][e0]);
            float4 b4 = *(const float4*)(&sh2[rl * 2 + rr][e0]);
            fma4(acc[rr], a4.x, cwf[0]); fma4(acc[rr], a4.y, cwf[1]);
            fma4(acc[rr], a4.z, cwf[2]); fma4(acc[rr], a4.w, cwf[3]);
            fma4(acc[rr], b4.x, cwl[0]); fma4(acc[rr], b4.y, cwl[1]);
            fma4(acc[rr], b4.z, cwl[2]); fma4(acc[rr], b4.w, cwl[3]);
        }
        #pragma unroll
        for (int ee = 0; ee < 4; ++ee) { cwf[ee] = nwf[ee]; cwl[ee] = nwl[ee]; }
    }

    #pragma unroll
    for (int rr = 0; rr < 2; ++rr) {
        long row = row0 + rl * 2 + rr;
        float4 s;
        s.x = 1.0f / (1.0f + __expf(-acc[rr].x));
        s.y = 1.0f / (1.0f + __expf(-acc[rr].y));
        s.z = 1.0f / (1.0f + __expf(-acc[rr].z));
        s.w = 1.0f / (1.0f + __expf(-acc[rr].w));
        *(float4*)(qsig + row * D + dq * 4) = s;
    }
}

// ---------------------------------------------------------------------------
// K3: partial num/den over an n-chunk (R9 ping-pong; ek/ekv now bf16).
// ---------------------------------------------------------------------------
#define PT 20
#define TS 32
__global__ __launch_bounds__(128) void aft_part_kernel(
        const float* __restrict__ cur_dist,
        const float* __restrict__ ninf,
        const ushortx* __restrict__ ekh,
        const ushortx* __restrict__ evh,
        const float* __restrict__ log_scale,
        const float* __restrict__ aft_alpha,
        float* __restrict__ pnum,
        float* __restrict__ pden,
        int NC, int L) {
    __shared__ float eb[2][TS][33];
    const int t = threadIdx.x;
    const int dq = t & 31;
    const int pl = t >> 5;
    const int pl5 = pl * 5;
    const int b    = blockIdx.x % B;            // b fastest -> XCD locality
    const int rest = blockIdx.x / B;
    const int c    = rest % NC;
    const int pt   = rest / NC;
    const int p0 = pt * PT;
    const int n_begin = c * L;
    const int n_end = min(N, n_begin + L);
    const float lsA = log_scale[0] * aft_alpha[0];

    float4 num[5], den[5];
    #pragma unroll
    for (int i = 0; i < 5; ++i) {
        num[i] = make_float4(0.f, 0.f, 0.f, 0.f);
        den[i] = make_float4(0.f, 0.f, 0.f, 0.f);
    }

    float rv[5];
    int n0 = n_begin;
    int ts = min(TS, n_end - n0);

    #pragma unroll
    for (int k = 0; k < 5; ++k) {
        int s = t + k * 128;
        int pp = s >> 5, nl = s & 31;
        rv[k] = 0.f;
        if (nl < ts) {
            long idx = ((long)b * P + p0 + pp) * N + (n0 + nl);
            rv[k] = fmaf(-lsA, cur_dist[idx], ninf[idx]);
        }
    }

    int buf = 0;
    while (n0 < n_end) {
        #pragma unroll
        for (int k = 0; k < 5; ++k) {
            int s = t + k * 128;
            int pp = s >> 5, nl = s & 31;
            if (nl < ts) eb[buf][nl][pp] = __expf(rv[k]);
        }
        __syncthreads();

        const int n0n = n0 + ts;
        const int tsn = min(TS, n_end - n0n);
        if (n0n < n_end) {
            #pragma unroll
            for (int k = 0; k < 5; ++k) {
                int s = t + k * 128;
                int pp = s >> 5, nl = s & 31;
                rv[k] = 0.f;
                if (nl < tsn) {
                    long idx = ((long)b * P + p0 + pp) * N + (n0n + nl);
                    rv[k] = fmaf(-lsA, cur_dist[idx], ninf[idx]);
                }
            }
        }

        const ushortx* ekb = ekh + ((long)b * N + n0) * D + dq * 4;
        const ushortx* evb = evh + ((long)b * N + n0) * D + dq * 4;
        #pragma unroll 4
        for (int j = 0; j < ts; ++j) {
            ushort4 eku = *(const ushort4*)(ekb + (long)j * D);
            ushort4 evu = *(const ushort4*)(evb + (long)j * D);
            float4 ekq = make_float4(bf2f(eku.x), bf2f(eku.y),
                                     bf2f(eku.z), bf2f(eku.w));
            float4 evq = make_float4(bf2f(evu.x), bf2f(evu.y),
                                     bf2f(evu.z), bf2f(evu.w));
            float e0 = eb[buf][j][pl5 + 0];
            float e1 = eb[buf][j][pl5 + 1];
            float e2 = eb[buf][j][pl5 + 2];
            float e3 = eb[buf][j][pl5 + 3];
            float e4 = eb[buf][j][pl5 + 4];
            fma4(num[0], e0, evq); fma4(den[0], e0, ekq);
            fma4(num[1], e1, evq); fma4(den[1], e1, ekq);
            fma4(num[2], e2, evq); fma4(den[2], e2, ekq);
            fma4(num[3], e3, evq); fma4(den[3], e3, ekq);
            fma4(num[4], e4, evq); fma4(den[4], e4, ekq);
        }
        buf ^= 1;
        n0 = n0n;
        ts = tsn;
    }

    #pragma unroll
    for (int r = 0; r < 5; ++r) {
        int p = p0 + pl5 + r;
        long o = (((long)c * B + b) * P + p) * D + dq * 4;
        *(float4*)(pnum + o) = num[r];
        *(float4*)(pden + o) = den[r];
    }
}

// ---------------------------------------------------------------------------
// K3b: reduce chunks -> aft = qsig * num / den.
// ---------------------------------------------------------------------------
__global__ __launch_bounds__(256) void aft_reduce_kernel(
        const float* __restrict__ pnum,
        const float* __restrict__ pden,
        const float* __restrict__ qsig,
        float* __restrict__ aft,
        int NC) {
    const long i = (long)blockIdx.x * 256 + threadIdx.x;
    const long BPD = (long)B * P * D;
    float n = 0.f, d = 0.f;
    for (int c = 0; c < NC; ++c) {
        n += pnum[(long)c * BPD + i];
        d += pden[(long)c * BPD + i];
    }
    aft[i] = qsig[i] * n / d;
}

// ---------------------------------------------------------------------------
// K4a: score_part — bounded scores, no-max softmax; atomics for denominators.
// ---------------------------------------------------------------------------
#define PT2 10
#define SC 4
__global__ __launch_bounds__(128) void score_part_kernel(
        const float* __restrict__ aft,
        const float* __restrict__ nodesT,
        const float* __restrict__ cur_dist,
        const float* __restrict__ ninf,
        const float* __restrict__ log_scale,
        const float* __restrict__ dist_alpha,
        float* __restrict__ out,
        float* __restrict__ sums) {
    __shared__ float sa[PT2][D];
    __shared__ float red[2][PT2];
    const int t = threadIdx.x;
    const int wid = t >> 6;
    const int b    = blockIdx.x % B;
    const int rest = blockIdx.x / B;
    const int c    = rest % SC;
    const int pt   = rest / SC;
    const int p0 = pt * PT2;
    const float lsA = log_scale[0] * dist_alpha[0];

    for (int i = t; i < PT2 * D; i += 128) {
        sa[i >> 7][i & 127] = aft[((long)b * P + p0) * D + i];
    }
    __syncthreads();

    const int n0 = c * 256 + t * 2;
    const bool act = (n0 < N);
    const int ncl = act ? n0 : 0;
    const float* ntb = nodesT + (long)b * D * N;

    float2 acc[PT2];
    #pragma unroll
    for (int i = 0; i < PT2; ++i) acc[i] = make_float2(0.f, 0.f);

    float2 cx[4];
    #pragma unroll
    for (int ee = 0; ee < 4; ++ee)
        cx[ee] = *(const float2*)(ntb + (long)ee * N + ncl);

    for (int e0 = 0; e0 < D; e0 += 4) {
        float2 nx[4];
        if (e0 + 4 < D) {
            #pragma unroll
            for (int ee = 0; ee < 4; ++ee)
                nx[ee] = *(const float2*)(ntb + (long)(e0 + 4 + ee) * N + ncl);
        }
        #pragma unroll
        for (int i = 0; i < PT2; ++i) {
            float4 a4 = *(const float4*)(&sa[i][e0]);
            acc[i].x = fmaf(cx[0].x, a4.x, acc[i].x);
            acc[i].x = fmaf(cx[1].x, a4.y, acc[i].x);
            acc[i].x = fmaf(cx[2].x, a4.z, acc[i].x);
            acc[i].x = fmaf(cx[3].x, a4.w, acc[i].x);
            acc[i].y = fmaf(cx[0].y, a4.x, acc[i].y);
            acc[i].y = fmaf(cx[1].y, a4.y, acc[i].y);
            acc[i].y = fmaf(cx[2].y, a4.z, acc[i].y);
            acc[i].y = fmaf(cx[3].y, a4.w, acc[i].y);
        }
        #pragma unroll
        for (int ee = 0; ee < 4; ++ee) cx[ee] = nx[ee];
    }

    #pragma unroll
    for (int i = 0; i < PT2; ++i) {
        float2 ev = make_float2(0.f, 0.f);
        if (act) {
            long idx = ((long)b * P + p0 + i) * N + n0;
            float2 cd = *(const float2*)(cur_dist + idx);
            float2 nf = *(const float2*)(ninf + idx);
            float sx = fmaf(acc[i].x, SQRT_D_INV, -lsA * cd.x);
            float sy = fmaf(acc[i].y, SQRT_D_INV, -lsA * cd.y);
            float ax = fabsf(sx), ay = fabsf(sy);
            float rx = 1.f - 2.f / (__expf(2.f * ax) + 1.f);
            float ry = 1.f - 2.f / (__expf(2.f * ay) + 1.f);
            float scx = CLIPV * copysignf(rx, sx) + nf.x;
            float scy = CLIPV * copysignf(ry, sy) + nf.y;
            ev.x = __expf(scx);
            ev.y = __expf(scy);
            *(float2*)(out + idx) = ev;
        }
        float s = ev.x + ev.y;
        #pragma unroll
        for (int o = 1; o < 64; o <<= 1) s += __shfl_xor(s, o, 64);
        if ((t & 63) == 0) red[wid][i] = s;
    }
    __syncthreads();
    if (t < PT2) {
        atomicAdd(&sums[b * P + p0 + t], red[0][t] + red[1][t]);
    }
}

// ---------------------------------------------------------------------------
// K4b: normalize — out[b,p,n] /= sums[b,p].
// ---------------------------------------------------------------------------
__global__ __launch_bounds__(256) void normalize_kernel(
        float* __restrict__ out, const float* __restrict__ sums) {
    const int row = blockIdx.x;
    const int t = threadIdx.x;
    const float inv = 1.0f / sums[row];
    float4* r = (float4*)(out + (long)row * N);
    if (t < N / 4) {
        float4 v = r[t];
        v.x *= inv; v.y *= inv; v.z *= inv; v.w *= inv;
        r[t] = v;
    }
}

// ---------------------------------------------------------------------------
extern "C" void kernel_launch(void* const* d_in, const int* in_sizes, int n_in,
                              void* d_out, int out_size, void* d_ws, size_t ws_size,
                              hipStream_t stream) {
    const float* nodes      = (const float*)d_in[0];
    const float* q1         = (const float*)d_in[1];
    const float* qlast      = (const float*)d_in[2];
    const float* cur_dist   = (const float*)d_in[3];
    const float* ninf       = (const float*)d_in[4];
    const float* log_scale  = (const float*)d_in[5];
    const float* Wqf        = (const float*)d_in[6];
    const float* Wql        = (const float*)d_in[7];
    const float* Wk         = (const float*)d_in[8];
    const float* Wv         = (const float*)d_in[9];
    const float* dist_alpha = (const float*)d_in[10];
    const float* aft_alpha  = (const float*)d_in[11];
    float* out = (float*)d_out;

    const long BND = (long)B * N * D;   // 4,096,000
    const long BPD = (long)B * P * D;   //   409,600
    const long W2  = (long)D * D;

    char* base = (char*)d_ws;
    size_t off = 0;
    ushortx* ekh = (ushortx*)(base + off); off += (size_t)BND * 2;   // bf16
    ushortx* evh = (ushortx*)(base + off); off += (size_t)BND * 2;   // bf16
    float* qsig   = (float*)(base + off); off += (size_t)BPD * 4;
    float* aft    = (float*)(base + off); off += (size_t)BPD * 4;
    float* wkT    = (float*)(base + off); off += (size_t)W2 * 4;
    float* wvT    = (float*)(base + off); off += (size_t)W2 * 4;
    float* wqfT   = (float*)(base + off); off += (size_t)W2 * 4;
    float* wqlT   = (float*)(base + off); off += (size_t)W2 * 4;
    float* nodesT = (float*)(base + off); off += (size_t)BND * 4;
    float* sums   = (float*)(base + off); off += (size_t)B * P * 4;
    float* pnum   = (float*)(base + off);

    long avail = (long)((ws_size - off) / 4);
    int NC = (int)(avail / (2 * BPD));
    if (NC < 1) NC = 1;
    if (NC > 12) NC = 12;
    int L = (N + NC - 1) / NC;
    NC = (N + L - 1) / L;
    float* pden = pnum + (long)NC * BPD;

    hipMemsetAsync(sums, 0, (size_t)B * P * sizeof(float), stream);
    prep_kernel<<<D + B * ((N + TT - 1) / TT), 256, 0, stream>>>(
        nodes, Wk, Wv, Wqf, Wql, wkT, wvT, wqfT, wqlT, nodesT);
    kv_kernel<<<(B * N) / R1, 256, 0, stream>>>(nodes, wkT, wvT, ekh, evh);
    q_kernel<<<(B * P) / R2, 256, 0, stream>>>(q1, qlast, wqfT, wqlT, qsig);
    aft_part_kernel<<<B * (P / PT) * NC, 128, 0, stream>>>(
        cur_dist, ninf, ekh, evh, log_scale, aft_alpha, pnum, pden, NC, L);
    aft_reduce_kernel<<<(int)(BPD / 256), 256, 0, stream>>>(pnum, pden, qsig, aft, NC);
    score_part_kernel<<<B * SC * (P / PT2), 128, 0, stream>>>(
        aft, nodesT, cur_dist, ninf, log_scale, dist_alpha, out, sums);
    normalize_kernel<<<B * P, 256, 0, stream>>>(out, sums);
}